// Round 1
// baseline (141.116 us; speedup 1.0000x reference)
//
#include <hip/hip_runtime.h>

// KroneckerProjection: out = X @ kron(A,B), factored — never materialize C.
//   X: [16384, 2048] fp32, A: [128,16], B: [16,512], out: [16384, 8192] fp32
//   T[j][k] = sum_i x[i*16+k] * A[i][j]   (per row, 16x16)
//   out[j*512+l] = sum_k T[j][k] * B[k][l]
// Memory-bound: 128 MiB read + 512 MiB write -> ~105 us floor at 6.3 TB/s.

#define P_DIM 128
#define Q_DIM 16
#define R_DIM 16
#define S_DIM 512
#define DIN   2048
#define DOUT  8192
#define ROWS_PER_BLOCK 8
#define GROUP 4

__global__ __launch_bounds__(256)
void kron_proj_kernel(const float* __restrict__ x,
                      const float* __restrict__ A,
                      const float* __restrict__ B,
                      float* __restrict__ out)
{
    __shared__ __align__(16) float A_lds[P_DIM * Q_DIM];     // 8 KiB
    __shared__ __align__(16) float x_lds[GROUP * DIN];       // 32 KiB
    __shared__ __align__(16) float T_lds[GROUP * Q_DIM * R_DIM]; // 4 KiB

    const int t = threadIdx.x;

    // ---- Stage A into LDS (once per block): 2048 floats = 512 float4
    {
        const float4* A4 = (const float4*)A;
        float4* AL4 = (float4*)A_lds;
        AL4[t] = A4[t];          // t in [0,256)
        AL4[t + 256] = A4[t + 256];
    }

    // ---- B into registers (once per block): this thread covers l0..l0+3
    const int lg = t & 127;       // 128 l-groups of 4 -> covers all 512 l
    const int l0 = lg * 4;
    float4 Breg[16];
#pragma unroll
    for (int k = 0; k < 16; ++k)
        Breg[k] = *(const float4*)(B + k * S_DIM + l0);

    const int row0 = blockIdx.x * ROWS_PER_BLOCK;

    // step-1 decomposition: slot covers (k, j0); wave id = row within group
    const int slot = t & 63;
    const int kk = slot & 15;
    const int j0 = (slot >> 4) * 4;
    const int rw = t >> 6;   // 0..3 : row within group for step 1
    const int rr = t >> 7;   // 0..1 : row parity for step 2

    for (int g = 0; g < ROWS_PER_BLOCK; g += GROUP) {
        __syncthreads();   // protect x_lds/T_lds from previous iteration

        // ---- Stage 4 rows of x (contiguous 8192 floats) into LDS
        {
            const float4* xg = (const float4*)(x + (size_t)(row0 + g) * DIN);
            float4* xl = (float4*)x_lds;
#pragma unroll
            for (int w = 0; w < 8; ++w)
                xl[w * 256 + t] = xg[w * 256 + t];
        }
        __syncthreads();

        // ---- Step 1: T[rw][j0..j0+3][kk], one wave per row
        {
            float acc0 = 0.f, acc1 = 0.f, acc2 = 0.f, acc3 = 0.f;
            const float* xr = x_lds + rw * DIN;
#pragma unroll 8
            for (int i = 0; i < P_DIM; ++i) {
                float xv = xr[i * 16 + kk];                       // broadcast-friendly
                float4 av = *(const float4*)(A_lds + i * 16 + j0); // row-contiguous
                acc0 = fmaf(xv, av.x, acc0);
                acc1 = fmaf(xv, av.y, acc1);
                acc2 = fmaf(xv, av.z, acc2);
                acc3 = fmaf(xv, av.w, acc3);
            }
            float* Tr = T_lds + rw * Q_DIM * R_DIM;
            Tr[(j0 + 0) * 16 + kk] = acc0;
            Tr[(j0 + 1) * 16 + kk] = acc1;
            Tr[(j0 + 2) * 16 + kk] = acc2;
            Tr[(j0 + 3) * 16 + kk] = acc3;
        }
        __syncthreads();

        // ---- Step 2: out[j][l0..l0+3] = sum_k T[j][k] * B[k][l]
#pragma unroll
        for (int rp = 0; rp < 2; ++rp) {
            const int r = rp * 2 + rr;
            const float* Tr = T_lds + r * Q_DIM * R_DIM;
            float* orow = out + (size_t)(row0 + g + r) * DOUT + l0;
#pragma unroll
            for (int j = 0; j < Q_DIM; ++j) {
                float4 t0 = *(const float4*)(Tr + j * 16 + 0);   // broadcast reads
                float4 t1 = *(const float4*)(Tr + j * 16 + 4);
                float4 t2 = *(const float4*)(Tr + j * 16 + 8);
                float4 t3 = *(const float4*)(Tr + j * 16 + 12);
                float tk[16] = { t0.x, t0.y, t0.z, t0.w,
                                 t1.x, t1.y, t1.z, t1.w,
                                 t2.x, t2.y, t2.z, t2.w,
                                 t3.x, t3.y, t3.z, t3.w };
                float4 acc = make_float4(0.f, 0.f, 0.f, 0.f);
#pragma unroll
                for (int k = 0; k < 16; ++k) {
                    acc.x = fmaf(tk[k], Breg[k].x, acc.x);
                    acc.y = fmaf(tk[k], Breg[k].y, acc.y);
                    acc.z = fmaf(tk[k], Breg[k].z, acc.z);
                    acc.w = fmaf(tk[k], Breg[k].w, acc.w);
                }
                *(float4*)(orow + j * S_DIM) = acc;   // coalesced across lanes
            }
        }
    }
}

extern "C" void kernel_launch(void* const* d_in, const int* in_sizes, int n_in,
                              void* d_out, int out_size, void* d_ws, size_t ws_size,
                              hipStream_t stream) {
    const float* x = (const float*)d_in[0];
    const float* A = (const float*)d_in[1];
    const float* B = (const float*)d_in[2];
    float* out = (float*)d_out;

    const int nrows = in_sizes[0] / DIN;          // 16384
    const int grid = nrows / ROWS_PER_BLOCK;      // 2048 blocks, 8/CU

    kron_proj_kernel<<<dim3(grid), dim3(256), 0, stream>>>(x, A, B, out);
}